// Round 1
// 165.861 us; speedup vs baseline: 1.0992x; 1.0992x over previous
//
#include <hip/hip_runtime.h>
#include <hip/hip_bf16.h>

// Problem constants
#define BB 64
#define TT 16384
#define DD 128
#define EE 256
#define NN 8
#define SS 1024
#define NCLS 18
#define NBLK 3
#define EPSV 1e-5f

typedef __bf16 bf16x8 __attribute__((ext_vector_type(8)));
typedef __bf16 bf16x4 __attribute__((ext_vector_type(4)));
typedef float f32x4 __attribute__((ext_vector_type(4)));
typedef unsigned short ushort_t;

__device__ __forceinline__ float silu_f(float z) {
    return z * __builtin_amdgcn_rcpf(1.0f + __expf(-z));
}
__device__ __forceinline__ unsigned int bfbits(float v) {
    return (unsigned int)__builtin_bit_cast(unsigned short, (__bf16)v);
}
__device__ __forceinline__ float bflow(unsigned int u) {
    return (float)__builtin_bit_cast(__bf16, (unsigned short)(u & 0xffffu));
}
__device__ __forceinline__ float bfhigh(unsigned int u) {
    return (float)__builtin_bit_cast(__bf16, (unsigned short)(u >> 16));
}
__device__ __forceinline__ ushort_t bfu(float v) {
    return __builtin_bit_cast(ushort_t, (__bf16)v);
}

// ---------------------------------------------------------------------------
// Merged weight pack: pc1_w [3][256][128] -> wpk1[L][ks4][nf16][lane64][e8]
//                     pc2_w [3][128][256] -> wpk2[L][ks8][nf8][lane64][e8]
// ---------------------------------------------------------------------------
__global__ __launch_bounds__(256) void k_pack(const float* __restrict__ w1,
                                              const float* __restrict__ w2,
                                              ushort_t* __restrict__ wpk1,
                                              ushort_t* __restrict__ wpk2) {
    const int t0 = blockIdx.x * 256 + threadIdx.x;
    const float* src;
    uint4* dst;
    if (t0 < 12288) {
        const int L = t0 >> 12;
        const int r = t0 & 4095;
        const int ks = r >> 10;
        const int r2 = r & 1023;
        const int nf = r2 >> 6;
        const int lane = r2 & 63;
        const int col = nf * 16 + (lane & 15);
        const int k0 = ks * 32 + (lane >> 4) * 8;
        src = w1 + ((size_t)L * EE + col) * DD + k0;
        dst = (uint4*)wpk1 + t0;
    } else {
        const int t = t0 - 12288;
        const int L = t >> 12;
        const int r = t & 4095;
        const int ks = r >> 9;
        const int r2 = r & 511;
        const int nf = r2 >> 6;
        const int lane = r2 & 63;
        const int col = nf * 16 + (lane & 15);
        const int k0 = ks * 32 + (lane >> 4) * 8;
        src = w2 + ((size_t)L * DD + col) * EE + k0;
        dst = (uint4*)wpk2 + t;
    }
    const float4 a = ((const float4*)src)[0];
    const float4 b = ((const float4*)src)[1];
    bf16x8 pk;
    pk[0] = (__bf16)a.x; pk[1] = (__bf16)a.y; pk[2] = (__bf16)a.z; pk[3] = (__bf16)a.w;
    pk[4] = (__bf16)b.x; pk[5] = (__bf16)b.y; pk[6] = (__bf16)b.z; pk[7] = (__bf16)b.w;
    *dst = __builtin_bit_cast(uint4, pk);
}

// ---------------------------------------------------------------------------
// Shared tail: LN + pc1 GEMM + silu -> xcT granules, fed from an LDS x-tile.
// xtile: bf16 [64][128] stored with 16B-chunk XOR swizzle:
//   ushort idx = row*128 + (((col>>3) ^ (row&7))<<3) + (col&7)
// A2 region at smem+16384: uint4[64*16], standard pc1 A-swizzle.
// ---------------------------------------------------------------------------
__device__ __forceinline__ void xt_store(ushort_t* xt16, int row, int col,
                                         ushort_t val) {
    xt16[row * 128 + (((col >> 3) ^ (row & 7)) << 3) + (col & 7)] = val;
}

__device__ __forceinline__ void ln_pc1_tail(
    char* smem, const int tid,
    const float* __restrict__ lng, const float* __restrict__ lnb,
    const ushort_t* __restrict__ wpk, const float* __restrict__ bias1,
    __bf16* __restrict__ xcT, const int bidx, const int sg0) {
    const uint4* xt = (const uint4*)smem;          // [64][16] chunk-swizzled
    uint4* A2 = (uint4*)(smem + 16384);            // [64*16]

    {
        const int row = tid >> 2;
        const int q = tid & 3;
        float v[32];
#pragma unroll
        for (int i = 0; i < 4; ++i) {
            const uint4 tv4 = xt[row * 16 + ((q * 4 + i) ^ (row & 7))];
            const bf16x8 tv = __builtin_bit_cast(bf16x8, tv4);
#pragma unroll
            for (int e2 = 0; e2 < 8; ++e2) v[i * 8 + e2] = (float)tv[e2];
        }
        float s1 = 0.0f, s2 = 0.0f;
#pragma unroll
        for (int i = 0; i < 32; ++i) { s1 += v[i]; s2 += v[i] * v[i]; }
        s1 += __shfl_xor(s1, 1); s2 += __shfl_xor(s2, 1);
        s1 += __shfl_xor(s1, 2); s2 += __shfl_xor(s2, 2);
        const float mean = s1 * (1.0f / 128.0f);
        const float rstd = rsqrtf(s2 * (1.0f / 128.0f) - mean * mean + EPSV);
        const float4* gp = (const float4*)(lng + q * 32);
        const float4* bp = (const float4*)(lnb + q * 32);
#pragma unroll
        for (int c = 0; c < 4; ++c) {
            float4 g0 = gp[2 * c], g1 = gp[2 * c + 1];
            float4 b0 = bp[2 * c], b1 = bp[2 * c + 1];
            const float gg[8] = {g0.x, g0.y, g0.z, g0.w, g1.x, g1.y, g1.z, g1.w};
            const float bb2[8] = {b0.x, b0.y, b0.z, b0.w, b1.x, b1.y, b1.z, b1.w};
            bf16x8 pk;
#pragma unroll
            for (int e2 = 0; e2 < 8; ++e2)
                pk[e2] = (__bf16)((v[c * 8 + e2] - mean) * rstd * gg[e2] + bb2[e2]);
            A2[(row * 16 + q * 4 + c) ^ (row & 7)] = __builtin_bit_cast(uint4, pk);
        }
    }
    __syncthreads();

    const int wv = tid >> 6;
    const int lane = tid & 63;
    const int lrow = lane & 15;
    const int lk = lane >> 4;
    const uint4* wq = (const uint4*)wpk;

    f32x4 acc[4][4] = {};
    for (int ks = 0; ks < 4; ++ks) {
        bf16x8 av[4], bw[4];
#pragma unroll
        for (int m = 0; m < 4; ++m) {
            const int idx = ((lrow + m * 16) * 16 + ks * 4 + lk) ^ (lrow & 7);
            av[m] = __builtin_bit_cast(bf16x8, A2[idx]);
        }
#pragma unroll
        for (int n = 0; n < 4; ++n) {
            const int nf = wv * 4 + n;
            bw[n] = __builtin_bit_cast(bf16x8, wq[(ks * 16 + nf) * 64 + lane]);
        }
#pragma unroll
        for (int m = 0; m < 4; ++m)
#pragma unroll
            for (int n = 0; n < 4; ++n)
                acc[m][n] = __builtin_amdgcn_mfma_f32_16x16x32_bf16(av[m], bw[n], acc[m][n], 0, 0, 0);
    }

#pragma unroll
    for (int n = 0; n < 4; ++n) {
        const int col = wv * 64 + n * 16 + lrow;
        const float bv = bias1[col];
#pragma unroll
        for (int m = 0; m < 4; ++m) {
            bf16x4 pk;
#pragma unroll
            for (int r = 0; r < 4; ++r)
                pk[r] = (__bf16)silu_f(acc[m][n][r] + bv);
            const int sg = sg0 + m * 2 + (lk >> 1);
            __bf16* dst = xcT + ((((size_t)bidx * 128 + sg) * EE + col) << 3) +
                          (lk & 1) * 4;
            *(bf16x4*)dst = pk;
        }
    }
}

// ---------------------------------------------------------------------------
// Kernel 1: stem MFMA GEMM, fused with layer-0 LN+pc1 tail.
// ---------------------------------------------------------------------------
__global__ __launch_bounds__(256) void k_stem_mfma(
    const float* __restrict__ in, const float* __restrict__ acc_w,
    const float* __restrict__ acc_b, const float* __restrict__ gyro_w,
    const float* __restrict__ gyro_b, const float* __restrict__ pos_emb,
    __bf16* __restrict__ x,
    const float* __restrict__ lng, const float* __restrict__ lnb,
    const ushort_t* __restrict__ wpk1, const float* __restrict__ pc1b,
    __bf16* __restrict__ xcT) {
    __shared__ __align__(16) char smem[49152];
    uint4* Wl = (uint4*)smem;             // 128*16 uint4 = 32 KB
    uint4* Al = (uint4*)(smem + 32768);   // 64*16 uint4 = 16 KB

    const int tid = threadIdx.x;
    const int rbase = blockIdx.x * 64;
    const int b = rbase >> 10;
    const int sbase = rbase & 1023;

    if (tid < 128) {
        const int d = tid;
        const float* wsrc = (d < 64) ? (acc_w + d * 48) : (gyro_w + (d - 64) * 48);
        float aw[48];
        const float4* wq4 = (const float4*)wsrc;
#pragma unroll
        for (int q = 0; q < 12; ++q) {
            float4 t = wq4[q];
            aw[q * 4 + 0] = t.x; aw[q * 4 + 1] = t.y;
            aw[q * 4 + 2] = t.z; aw[q * 4 + 3] = t.w;
        }
        const bool isacc = (d < 64);
#pragma unroll
        for (int cc = 0; cc < 12; ++cc) {
            unsigned int wb[8];
#pragma unroll
            for (int e = 0; e < 8; ++e) {
                const int j = cc * 8 + e;
                const int p = j / 6, rem = j % 6;
                float val;
                if (rem < 3) val = isacc ? aw[rem * 16 + p] : 0.0f;
                else         val = isacc ? 0.0f : aw[(rem - 3) * 16 + p];
                wb[e] = bfbits(val);
            }
            uint4 pk;
            pk.x = wb[0] | (wb[1] << 16);
            pk.y = wb[2] | (wb[3] << 16);
            pk.z = wb[4] | (wb[5] << 16);
            pk.w = wb[6] | (wb[7] << 16);
            Wl[d * 16 + (cc ^ (d & 7))] = pk;
        }
    }

    {
        const float* abase = in + (size_t)b * (TT * 6) + (size_t)sbase * 96;
#pragma unroll
        for (int it = 0; it < 3; ++it) {
            const int idx = it * 256 + tid;
            const int row = idx / 12;
            const int ch = idx % 12;
            const float* src = abase + row * 96 + ch * 8;
            const float4 t0 = *(const float4*)src;
            const float4 t1 = *(const float4*)(src + 4);
            uint4 pk;
            pk.x = bfbits(t0.x) | (bfbits(t0.y) << 16);
            pk.y = bfbits(t0.z) | (bfbits(t0.w) << 16);
            pk.z = bfbits(t1.x) | (bfbits(t1.y) << 16);
            pk.w = bfbits(t1.z) | (bfbits(t1.w) << 16);
            Al[row * 16 + (ch ^ (row & 7))] = pk;
        }
    }
    __syncthreads();

    const int wv = tid >> 6;
    const int lane = tid & 63;
    const int lrow = lane & 15;
    const int lk = lane >> 4;

    f32x4 acc[4][2] = {};
#pragma unroll
    for (int ks = 0; ks < 3; ++ks) {
        bf16x8 a[4], bf[2];
#pragma unroll
        for (int m = 0; m < 4; ++m) {
            const int row = m * 16 + lrow;
            a[m] = __builtin_bit_cast(bf16x8, Al[row * 16 + ((ks * 4 + lk) ^ (row & 7))]);
        }
#pragma unroll
        for (int n = 0; n < 2; ++n) {
            const int col = (wv * 2 + n) * 16 + lrow;
            bf[n] = __builtin_bit_cast(bf16x8, Wl[col * 16 + ((ks * 4 + lk) ^ (col & 7))]);
        }
#pragma unroll
        for (int m = 0; m < 4; ++m)
#pragma unroll
            for (int n = 0; n < 2; ++n)
                acc[m][n] = __builtin_amdgcn_mfma_f32_16x16x32_bf16(a[m], bf[n], acc[m][n], 0, 0, 0);
    }
    __syncthreads();  // GEMM done reading Wl/Al before xtile overlay

    ushort_t* xt16 = (ushort_t*)smem;
#pragma unroll
    for (int n = 0; n < 2; ++n) {
        const int col = (wv * 2 + n) * 16 + lrow;
        const float bv = (col < 64) ? acc_b[col] : gyro_b[col - 64];
#pragma unroll
        for (int m = 0; m < 4; ++m)
#pragma unroll
            for (int r = 0; r < 4; ++r) {
                const int row = m * 16 + lk * 4 + r;
                const float pe = pos_emb[(size_t)(sbase + row) * DD + col];
                const float xv = acc[m][n][r] + bv + pe;
                const __bf16 xb = (__bf16)xv;
                x[(size_t)(rbase + row) * DD + col] = xb;
                xt_store(xt16, row, col, __builtin_bit_cast(ushort_t, xb));
            }
    }
    __syncthreads();
    ln_pc1_tail(smem, tid, lng, lnb, wpk1, pc1b, xcT, b, sbase >> 3);
}

// ---------------------------------------------------------------------------
// Kernel 2 (FUSED): conv + BN + silu + scan -> LDS -> pc2 GEMM + residual,
// then (TAIL) next-layer LN + pc1 from the freshly computed x tile.
// Warmup reduced 32->24 steps (attenuation e^-12), guard cndmask removed via
// block-uniform sc==0 split.
// ---------------------------------------------------------------------------
template <int TAIL>
__global__ __launch_bounds__(256, 4) void k_scan_pc2(
    const __bf16* __restrict__ xcIn,    // [B][128][E][8]
    const ushort_t* __restrict__ wpk2_, // packed [8][8][64][8]
    const float* __restrict__ dw_w, const float* __restrict__ dw_b,
    const float* __restrict__ bn_g, const float* __restrict__ bn_b,
    const float* __restrict__ bn_mean, const float* __restrict__ bn_var,
    const float* __restrict__ Ap, const float* __restrict__ Bp,
    const float* __restrict__ Cp, const float* __restrict__ Dpp,
    const float* __restrict__ bias, __bf16* __restrict__ x,
    const float* __restrict__ lng, const float* __restrict__ lnb,
    const ushort_t* __restrict__ wpk1, const float* __restrict__ pc1b,
    __bf16* __restrict__ xcOut) {
    __shared__ __align__(16) char smem[32768];  // ym tile / xtile+A2 overlay

    const int tid = threadIdx.x;
    const int sc = blockIdx.x;      // 0..15
    const int b = blockIdx.y;

    // ---------------- phase 1: conv + BN + silu + scan -> LDS -------------
    {
        const int e = tid;
        const float scale = bn_g[e] * rsqrtf(bn_var[e] + EPSV);
        const float d0 = dw_w[e * 5 + 0] * scale, d1 = dw_w[e * 5 + 1] * scale,
                    d2 = dw_w[e * 5 + 2] * scale, d3 = dw_w[e * 5 + 3] * scale,
                    d4 = dw_w[e * 5 + 4] * scale;
        const float cbias = (dw_b[e] - bn_mean[e]) * scale + bn_b[e];
        const float Aexp = __expf(Ap[e]);
        float cb = 0.0f;
#pragma unroll
        for (int n = 0; n < 8; ++n) cb += Cp[e * 8 + n] * Bp[e * 8 + n];
        const float Dv = Dpp[e];

        const int sgbase = sc * 8 - 4;      // G[j] = granule sgbase + j
        const uint4* xq = (const uint4*)xcIn;
        uint4 G[13];
#pragma unroll
        for (int j = 0; j < 13; ++j) {
            const int sg = sgbase + j;
            G[j] = (sg >= 0 && sg < 128)
                       ? xq[((size_t)b * 128 + sg) * EE + e]
                       : make_uint4(0, 0, 0, 0);
        }

        __bf16* lbase = (__bf16*)smem;
        const int ehash = e >> 3;
        const int elow = e & 7;

        float g = 0.0f, pw6, pw7;
        if (sc != 0) {
            // 24-step warmup, no stores, no guards.
            pw6 = bflow(G[0].w); pw7 = bfhigh(G[0].w);
#pragma unroll
            for (int j = 1; j <= 3; ++j) {
                float cw[8];
                cw[0] = bflow(G[j].x); cw[1] = bfhigh(G[j].x);
                cw[2] = bflow(G[j].y); cw[3] = bfhigh(G[j].y);
                cw[4] = bflow(G[j].z); cw[5] = bfhigh(G[j].z);
                cw[6] = bflow(G[j].w); cw[7] = bfhigh(G[j].w);
                const float nh0 = bflow(G[j + 1].x);
                const float nh1 = bfhigh(G[j + 1].x);
#pragma unroll
                for (int u = 0; u < 8; ++u) {
                    const float xm2 = (u >= 2) ? cw[u - 2] : (u == 0 ? pw6 : pw7);
                    const float xm1 = (u >= 1) ? cw[u - 1] : pw7;
                    const float x0 = cw[u];
                    const float xp1 = (u < 7) ? cw[u + 1] : nh0;
                    const float xp2 = (u < 6) ? cw[u + 2] : (u == 6 ? nh0 : nh1);
                    const float z = xm2 * d0 + xm1 * d1 + x0 * d2 + xp1 * d3 +
                                    xp2 * d4 + cbias;
                    g = fmaf(Aexp, g, silu_f(z));
                }
                pw6 = cw[6]; pw7 = cw[7];
            }
        } else {
            pw6 = 0.0f; pw7 = 0.0f;   // sc==0: s<0 inputs are zero-padded
        }

#pragma unroll
        for (int j = 4; j <= 11; ++j) {
            float cw[8];
            cw[0] = bflow(G[j].x); cw[1] = bfhigh(G[j].x);
            cw[2] = bflow(G[j].y); cw[3] = bfhigh(G[j].y);
            cw[4] = bflow(G[j].z); cw[5] = bfhigh(G[j].z);
            cw[6] = bflow(G[j].w); cw[7] = bfhigh(G[j].w);
            const float nh0 = bflow(G[j + 1].x);
            const float nh1 = bfhigh(G[j + 1].x);

            float aa[8];
#pragma unroll
            for (int u = 0; u < 8; ++u) {
                const float xm2 = (u >= 2) ? cw[u - 2] : (u == 0 ? pw6 : pw7);
                const float xm1 = (u >= 1) ? cw[u - 1] : pw7;
                const float x0 = cw[u];
                const float xp1 = (u < 7) ? cw[u + 1] : nh0;
                const float xp2 = (u < 6) ? cw[u + 2] : (u == 6 ? nh0 : nh1);
                const float z = xm2 * d0 + xm1 * d1 + x0 * d2 + xp1 * d3 +
                                xp2 * d4 + cbias;
                aa[u] = silu_f(z);
            }
#pragma unroll
            for (int u = 0; u < 8; ++u) {
                g = fmaf(Aexp, g, aa[u]);
                const int srel = (j - 4) * 8 + u;
                lbase[srel * 256 + ((ehash ^ (srel & 7)) << 3) + elow] =
                    (__bf16)(cb * g + Dv * aa[u]);
            }
            pw6 = cw[6]; pw7 = cw[7];
        }
    }
    __syncthreads();

    // ---------------- phase 2: pc2 GEMM + bias + residual -----------------
    const size_t rbase = ((size_t)b << 10) + ((size_t)sc << 6);
    const int wv = tid >> 6;
    const int lane = tid & 63;
    const int lrow = lane & 15;
    const int lk = lane >> 4;
    const uint4* wq = (const uint4*)wpk2_;
    const uint4* Albd = (const uint4*)smem;

    f32x4 acc[4][2] = {};
    for (int ks = 0; ks < 8; ++ks) {
        bf16x8 a[4], bfr[2];
#pragma unroll
        for (int m = 0; m < 4; ++m) {
            const int idx = ((lrow + m * 16) * 32 + ks * 4 + lk) ^ (lrow & 7);
            a[m] = __builtin_bit_cast(bf16x8, Albd[idx]);
        }
#pragma unroll
        for (int n = 0; n < 2; ++n) {
            const int nf = wv * 2 + n;
            bfr[n] = __builtin_bit_cast(bf16x8, wq[(ks * 8 + nf) * 64 + lane]);
        }
#pragma unroll
        for (int m = 0; m < 4; ++m)
#pragma unroll
            for (int n = 0; n < 2; ++n)
                acc[m][n] = __builtin_amdgcn_mfma_f32_16x16x32_bf16(a[m], bfr[n], acc[m][n], 0, 0, 0);
    }
    if constexpr (TAIL) __syncthreads();  // done reading ym before xtile overlay

    ushort_t* xt16 = (ushort_t*)smem;
#pragma unroll
    for (int n = 0; n < 2; ++n) {
        const int col = wv * 32 + n * 16 + lrow;
        const float bv = bias[col];
#pragma unroll
        for (int m = 0; m < 4; ++m)
#pragma unroll
            for (int r = 0; r < 4; ++r) {
                const int row = m * 16 + lk * 4 + r;
                __bf16* xp = x + (rbase + row) * DD + col;
                const float xn = (float)*xp + acc[m][n][r] + bv;
                const __bf16 xb = (__bf16)xn;
                *xp = xb;
                if constexpr (TAIL)
                    xt_store(xt16, row, col, __builtin_bit_cast(ushort_t, xb));
            }
    }
    if constexpr (TAIL) {
        __syncthreads();
        ln_pc1_tail(smem, tid, lng, lnb, wpk1, pc1b, xcOut, b, sc * 8);
    }
}

// ---------------------------------------------------------------------------
// Final LN partial sums over 128-row chunks (x bf16).
// ---------------------------------------------------------------------------
__global__ __launch_bounds__(256) void k_finln_s1(
    const __bf16* __restrict__ x, float* __restrict__ partial) {
    const int chunk = blockIdx.x;
    const int b = blockIdx.y;
    const int tid = threadIdx.x;
    const int wv = tid >> 6;
    const int lane = tid & 63;
    const __bf16* xb = x + ((size_t)b * SS + chunk * 128) * DD;

    float a0 = 0.0f, a1 = 0.0f;
    for (int s = wv; s < 128; s += 4) {
        const unsigned int vv = *(const unsigned int*)(xb + (size_t)s * DD + lane * 2);
        const float vx = bflow(vv);
        const float vy = bfhigh(vv);
        float s1 = vx + vy;
        float s2 = vx * vx + vy * vy;
#pragma unroll
        for (int m = 1; m <= 32; m <<= 1) {
            s1 += __shfl_xor(s1, m);
            s2 += __shfl_xor(s2, m);
        }
        const float mean = s1 * (1.0f / 128.0f);
        const float rstd = rsqrtf(s2 * (1.0f / 128.0f) - mean * mean + EPSV);
        a0 += (vx - mean) * rstd;
        a1 += (vy - mean) * rstd;
    }
    __shared__ float red[4][128];
    red[wv][lane * 2] = a0;
    red[wv][lane * 2 + 1] = a1;
    __syncthreads();
    if (tid < 128) {
        partial[((size_t)b * 8 + chunk) * 128 + tid] =
            red[0][tid] + red[1][tid] + red[2][tid] + red[3][tid];
    }
}

// ---------------------------------------------------------------------------
// Head (finln stage-2 fused in) + softmax. Block per b.
// ---------------------------------------------------------------------------
__global__ __launch_bounds__(256) void k_head(
    const float* __restrict__ partial, const float* __restrict__ fg,
    const float* __restrict__ fb, const float* __restrict__ hw1,
    const float* __restrict__ hb1, const float* __restrict__ hw2,
    const float* __restrict__ hb2, float* __restrict__ out) {
    const int b = blockIdx.x;
    const int tid = threadIdx.x;
    __shared__ float xmb[128];
    __shared__ float hh[256];
    __shared__ float lg[18];
    __shared__ float eg[18];

    if (tid < 128) {
        float s = 0.0f;
#pragma unroll
        for (int c = 0; c < 8; ++c)
            s += partial[((size_t)b * 8 + c) * 128 + tid];
        xmb[tid] = fg[tid] * (s * (1.0f / (float)SS)) + fb[tid];
    }
    __syncthreads();

    float z = hb1[tid];
    for (int k = 0; k < 128; ++k) z += xmb[k] * hw1[k * 256 + tid];
    hh[tid] = z / (1.0f + expf(-z));
    __syncthreads();

    if (tid < NCLS) {
        float a = hb2[tid];
        for (int k = 0; k < 256; ++k) a += hh[k] * hw2[k * NCLS + tid];
        lg[tid] = a;
    }
    __syncthreads();
    if (tid < NCLS) {
        float m = lg[0];
        for (int j = 1; j < NCLS; ++j) m = fmaxf(m, lg[j]);
        eg[tid] = expf(lg[tid] - m);
    }
    __syncthreads();
    if (tid < NCLS) {
        float ssum = 0.0f;
        for (int j = 0; j < NCLS; ++j) ssum += eg[j];
        out[b * NCLS + tid] = eg[tid] / ssum;
    }
}

// ---------------------------------------------------------------------------
extern "C" void kernel_launch(void* const* d_in, const int* in_sizes, int n_in,
                              void* d_out, int out_size, void* d_ws, size_t ws_size,
                              hipStream_t stream) {
    const float* inputs  = (const float*)d_in[0];
    const float* acc_w   = (const float*)d_in[1];
    const float* acc_b   = (const float*)d_in[2];
    const float* gyro_w  = (const float*)d_in[3];
    const float* gyro_b  = (const float*)d_in[4];
    const float* pos_emb = (const float*)d_in[5];
    const float* ln_g    = (const float*)d_in[6];
    const float* ln_b    = (const float*)d_in[7];
    const float* pc1_w   = (const float*)d_in[8];
    const float* pc1_b   = (const float*)d_in[9];
    const float* dw_w    = (const float*)d_in[10];
    const float* dw_b    = (const float*)d_in[11];
    const float* bn_g    = (const float*)d_in[12];
    const float* bn_b    = (const float*)d_in[13];
    const float* bn_mean = (const float*)d_in[14];
    const float* bn_var  = (const float*)d_in[15];
    const float* Ap      = (const float*)d_in[16];
    const float* Bp      = (const float*)d_in[17];
    const float* Cp      = (const float*)d_in[18];
    const float* Dp      = (const float*)d_in[19];
    const float* pc2_w   = (const float*)d_in[20];
    const float* pc2_b   = (const float*)d_in[21];
    const float* fln_g   = (const float*)d_in[22];
    const float* fln_b   = (const float*)d_in[23];
    const float* hw1     = (const float*)d_in[24];
    const float* hb1     = (const float*)d_in[25];
    const float* hw2     = (const float*)d_in[26];
    const float* hb2     = (const float*)d_in[27];

    const size_t nx  = (size_t)BB * SS * DD;   // 8388608
    const size_t nxc = (size_t)BB * SS * EE;   // 16777216

    ushort_t* wsu = (ushort_t*)d_ws;
    ushort_t* xb   = wsu;                       // bf16 x [M,128]
    ushort_t* xc0  = xb + nx;                   // bf16 xcT ping
    ushort_t* xc1  = xc0 + nxc;                 // bf16 xcT pong
    ushort_t* wpk1 = xc1 + nxc;
    ushort_t* wpk2 = wpk1 + 3 * 32768;
    float* partial = (float*)(wpk2 + 3 * 32768);

    __bf16* x    = (__bf16*)xb;
    __bf16* xcT0 = (__bf16*)xc0;
    __bf16* xcT1 = (__bf16*)xc1;

    k_pack<<<96, 256, 0, stream>>>(pc1_w, pc2_w, wpk1, wpk2);

    // stem + layer-0 LN/pc1 tail -> xcT0
    k_stem_mfma<<<1024, 256, 0, stream>>>(inputs, acc_w, acc_b, gyro_w, gyro_b,
                                          pos_emb, x,
                                          ln_g, ln_b, wpk1, pc1_b, xcT0);

    // layer 0: reads xcT0, tail writes layer-1 xcT1
    k_scan_pc2<1><<<dim3(16, BB), 256, 0, stream>>>(
        xcT0, wpk2,
        dw_w, dw_b, bn_g, bn_b, bn_mean, bn_var,
        Ap, Bp, Cp, Dp, pc2_b, x,
        ln_g + DD, ln_b + DD, wpk1 + 32768, pc1_b + EE, xcT1);

    // layer 1: reads xcT1, tail writes layer-2 xcT0
    k_scan_pc2<1><<<dim3(16, BB), 256, 0, stream>>>(
        xcT1, wpk2 + 32768,
        dw_w + EE * 5, dw_b + EE, bn_g + EE, bn_b + EE,
        bn_mean + EE, bn_var + EE,
        Ap + EE, Bp + EE * NN, Cp + EE * NN, Dp + EE,
        pc2_b + DD, x,
        ln_g + 2 * DD, ln_b + 2 * DD, wpk1 + 2 * 32768, pc1_b + 2 * EE, xcT0);

    // layer 2: reads xcT0, no tail
    k_scan_pc2<0><<<dim3(16, BB), 256, 0, stream>>>(
        xcT0, wpk2 + 2 * 32768,
        dw_w + 2 * EE * 5, dw_b + 2 * EE, bn_g + 2 * EE, bn_b + 2 * EE,
        bn_mean + 2 * EE, bn_var + 2 * EE,
        Ap + 2 * EE, Bp + 2 * EE * NN, Cp + 2 * EE * NN, Dp + 2 * EE,
        pc2_b + 2 * DD, x,
        nullptr, nullptr, nullptr, nullptr, nullptr);

    k_finln_s1<<<dim3(8, BB), 256, 0, stream>>>(x, partial);
    k_head<<<BB, 256, 0, stream>>>(partial, fln_g, fln_b, hw1, hb1, hw2, hb2,
                                   (float*)d_out);
}

// Round 2
// 159.384 us; speedup vs baseline: 1.1438x; 1.0406x over previous
//
#include <hip/hip_runtime.h>
#include <hip/hip_bf16.h>

// Problem constants
#define BB 64
#define TT 16384
#define DD 128
#define EE 256
#define NN 8
#define SS 1024
#define NCLS 18
#define NBLK 3
#define EPSV 1e-5f

typedef __bf16 bf16x8 __attribute__((ext_vector_type(8)));
typedef __bf16 bf16x4 __attribute__((ext_vector_type(4)));
typedef float f32x4 __attribute__((ext_vector_type(4)));
typedef unsigned short ushort_t;

__device__ __forceinline__ float silu_f(float z) {
    return z * __builtin_amdgcn_rcpf(1.0f + __expf(-z));
}
__device__ __forceinline__ unsigned int bfbits(float v) {
    return (unsigned int)__builtin_bit_cast(unsigned short, (__bf16)v);
}
__device__ __forceinline__ float bflow(unsigned int u) {
    return (float)__builtin_bit_cast(__bf16, (unsigned short)(u & 0xffffu));
}
__device__ __forceinline__ float bfhigh(unsigned int u) {
    return (float)__builtin_bit_cast(__bf16, (unsigned short)(u >> 16));
}

// ---------------------------------------------------------------------------
// Merged pack: pc1_w -> wpk1[L][ks4][nf16][lane64][e8]
//              pc2_w -> wpk2[L][ks8][nf8][lane64][e8]
//              scan params -> sparm[L][e][12] = {d0..d3, d4,cbias,Aexp,cb, Dv,...}
// ---------------------------------------------------------------------------
__global__ __launch_bounds__(256) void k_pack(
    const float* __restrict__ w1, const float* __restrict__ w2,
    const float* __restrict__ dw_w, const float* __restrict__ dw_b,
    const float* __restrict__ bn_g, const float* __restrict__ bn_b,
    const float* __restrict__ bn_mean, const float* __restrict__ bn_var,
    const float* __restrict__ Ap, const float* __restrict__ Bp,
    const float* __restrict__ Cp, const float* __restrict__ Dp,
    ushort_t* __restrict__ wpk1, ushort_t* __restrict__ wpk2,
    float* __restrict__ sparm) {
    const int t0 = blockIdx.x * 256 + threadIdx.x;
    if (t0 >= 24576) {
        const int t = t0 - 24576;
        if (t >= 768) return;
        const int le = t;  // L*256+e
        const float scale = bn_g[le] * rsqrtf(bn_var[le] + EPSV);
        float cb = 0.0f;
#pragma unroll
        for (int n = 0; n < 8; ++n) cb += Cp[le * 8 + n] * Bp[le * 8 + n];
        float* dst = sparm + (size_t)le * 12;
        dst[0] = dw_w[le * 5 + 0] * scale;
        dst[1] = dw_w[le * 5 + 1] * scale;
        dst[2] = dw_w[le * 5 + 2] * scale;
        dst[3] = dw_w[le * 5 + 3] * scale;
        dst[4] = dw_w[le * 5 + 4] * scale;
        dst[5] = (dw_b[le] - bn_mean[le]) * scale + bn_b[le];
        dst[6] = __expf(Ap[le]);
        dst[7] = cb;
        dst[8] = Dp[le];
        dst[9] = 0.0f; dst[10] = 0.0f; dst[11] = 0.0f;
        return;
    }
    const float* src;
    uint4* dst;
    if (t0 < 12288) {
        const int L = t0 >> 12;
        const int r = t0 & 4095;
        const int ks = r >> 10;
        const int r2 = r & 1023;
        const int nf = r2 >> 6;
        const int lane = r2 & 63;
        const int col = nf * 16 + (lane & 15);
        const int k0 = ks * 32 + (lane >> 4) * 8;
        src = w1 + ((size_t)L * EE + col) * DD + k0;
        dst = (uint4*)wpk1 + t0;
    } else {
        const int t = t0 - 12288;
        const int L = t >> 12;
        const int r = t & 4095;
        const int ks = r >> 9;
        const int r2 = r & 511;
        const int nf = r2 >> 6;
        const int lane = r2 & 63;
        const int col = nf * 16 + (lane & 15);
        const int k0 = ks * 32 + (lane >> 4) * 8;
        src = w2 + ((size_t)L * DD + col) * EE + k0;
        dst = (uint4*)wpk2 + t;
    }
    const float4 a = ((const float4*)src)[0];
    const float4 b = ((const float4*)src)[1];
    bf16x8 pk;
    pk[0] = (__bf16)a.x; pk[1] = (__bf16)a.y; pk[2] = (__bf16)a.z; pk[3] = (__bf16)a.w;
    pk[4] = (__bf16)b.x; pk[5] = (__bf16)b.y; pk[6] = (__bf16)b.z; pk[7] = (__bf16)b.w;
    *dst = __builtin_bit_cast(uint4, pk);
}

// ---------------------------------------------------------------------------
// Shared tail: LN + pc1 GEMM + silu -> xcT granules, fed from an LDS x-tile.
// xtile: bf16 [MROWS][128], 16B-chunk XOR swizzle:
//   ushort idx = row*128 + (((col>>3) ^ (row&7))<<3) + (col&7)
// A2 region at smem + MROWS*256 bytes: uint4[MROWS*16], pc1 A-swizzle.
// ---------------------------------------------------------------------------
__device__ __forceinline__ void xt_store(ushort_t* xt16, int row, int col,
                                         ushort_t val) {
    xt16[row * 128 + (((col >> 3) ^ (row & 7)) << 3) + (col & 7)] = val;
}

template <int MROWS>
__device__ __forceinline__ void ln_pc1_tail(
    char* smem, const int tid,
    const float* __restrict__ lng, const float* __restrict__ lnb,
    const ushort_t* __restrict__ wpk, const float* __restrict__ bias1,
    __bf16* __restrict__ xcT, const int bidx, const int sg0) {
    constexpr int TPR = 256 / MROWS;   // threads per row: 4 or 8
    constexpr int CPT = 16 / TPR;      // 16B chunks per thread: 4 or 2
    constexpr int MT = MROWS / 16;     // 16-row GEMM tiles: 4 or 2
    const uint4* xt = (const uint4*)smem;              // [MROWS][16] swizzled
    uint4* A2 = (uint4*)(smem + MROWS * 256);          // [MROWS*16]

    {
        const int row = tid / TPR;
        const int q = tid % TPR;
        float v[CPT * 8];
#pragma unroll
        for (int i = 0; i < CPT; ++i) {
            const uint4 tv4 = xt[row * 16 + ((q * CPT + i) ^ (row & 7))];
            const bf16x8 tv = __builtin_bit_cast(bf16x8, tv4);
#pragma unroll
            for (int e2 = 0; e2 < 8; ++e2) v[i * 8 + e2] = (float)tv[e2];
        }
        float s1 = 0.0f, s2 = 0.0f;
#pragma unroll
        for (int i = 0; i < CPT * 8; ++i) { s1 += v[i]; s2 += v[i] * v[i]; }
        s1 += __shfl_xor(s1, 1); s2 += __shfl_xor(s2, 1);
        s1 += __shfl_xor(s1, 2); s2 += __shfl_xor(s2, 2);
        if constexpr (TPR == 8) {
            s1 += __shfl_xor(s1, 4); s2 += __shfl_xor(s2, 4);
        }
        const float mean = s1 * (1.0f / 128.0f);
        const float rstd = rsqrtf(s2 * (1.0f / 128.0f) - mean * mean + EPSV);
        const float4* gp4 = (const float4*)lng;
        const float4* bp4 = (const float4*)lnb;
#pragma unroll
        for (int c = 0; c < CPT; ++c) {
            const int ci = q * CPT + c;
            float4 g0 = gp4[ci * 2], g1 = gp4[ci * 2 + 1];
            float4 b0 = bp4[ci * 2], b1 = bp4[ci * 2 + 1];
            const float gg[8] = {g0.x, g0.y, g0.z, g0.w, g1.x, g1.y, g1.z, g1.w};
            const float bb2[8] = {b0.x, b0.y, b0.z, b0.w, b1.x, b1.y, b1.z, b1.w};
            bf16x8 pk;
#pragma unroll
            for (int e2 = 0; e2 < 8; ++e2)
                pk[e2] = (__bf16)((v[c * 8 + e2] - mean) * rstd * gg[e2] + bb2[e2]);
            A2[(row * 16 + ci) ^ (row & 7)] = __builtin_bit_cast(uint4, pk);
        }
    }
    __syncthreads();

    const int wv = tid >> 6;
    const int lane = tid & 63;
    const int lrow = lane & 15;
    const int lk = lane >> 4;
    const uint4* wq = (const uint4*)wpk;

    f32x4 acc[MT][4] = {};
    for (int ks = 0; ks < 4; ++ks) {
        bf16x8 av[MT], bw[4];
#pragma unroll
        for (int m = 0; m < MT; ++m) {
            const int idx = ((lrow + m * 16) * 16 + ks * 4 + lk) ^ (lrow & 7);
            av[m] = __builtin_bit_cast(bf16x8, A2[idx]);
        }
#pragma unroll
        for (int n = 0; n < 4; ++n) {
            const int nf = wv * 4 + n;
            bw[n] = __builtin_bit_cast(bf16x8, wq[(ks * 16 + nf) * 64 + lane]);
        }
#pragma unroll
        for (int m = 0; m < MT; ++m)
#pragma unroll
            for (int n = 0; n < 4; ++n)
                acc[m][n] = __builtin_amdgcn_mfma_f32_16x16x32_bf16(av[m], bw[n], acc[m][n], 0, 0, 0);
    }

#pragma unroll
    for (int n = 0; n < 4; ++n) {
        const int col = wv * 64 + n * 16 + lrow;
        const float bv = bias1[col];
#pragma unroll
        for (int m = 0; m < MT; ++m) {
            bf16x4 pk;
#pragma unroll
            for (int r = 0; r < 4; ++r)
                pk[r] = (__bf16)silu_f(acc[m][n][r] + bv);
            const int sg = sg0 + m * 2 + (lk >> 1);
            __bf16* dst = xcT + ((((size_t)bidx * 128 + sg) * EE + col) << 3) +
                          (lk & 1) * 4;
            *(bf16x4*)dst = pk;
        }
    }
}

// ---------------------------------------------------------------------------
// Kernel 1: stem MFMA GEMM, fused with layer-0 LN+pc1 tail (64-row tiles).
// ---------------------------------------------------------------------------
__global__ __launch_bounds__(256) void k_stem_mfma(
    const float* __restrict__ in, const float* __restrict__ acc_w,
    const float* __restrict__ acc_b, const float* __restrict__ gyro_w,
    const float* __restrict__ gyro_b, const float* __restrict__ pos_emb,
    __bf16* __restrict__ x,
    const float* __restrict__ lng, const float* __restrict__ lnb,
    const ushort_t* __restrict__ wpk1, const float* __restrict__ pc1b,
    __bf16* __restrict__ xcT) {
    __shared__ __align__(16) char smem[49152];
    uint4* Wl = (uint4*)smem;             // 128*16 uint4 = 32 KB
    uint4* Al = (uint4*)(smem + 32768);   // 64*16 uint4 = 16 KB

    const int tid = threadIdx.x;
    const int rbase = blockIdx.x * 64;
    const int b = rbase >> 10;
    const int sbase = rbase & 1023;

    if (tid < 128) {
        const int d = tid;
        const float* wsrc = (d < 64) ? (acc_w + d * 48) : (gyro_w + (d - 64) * 48);
        float aw[48];
        const float4* wq4 = (const float4*)wsrc;
#pragma unroll
        for (int q = 0; q < 12; ++q) {
            float4 t = wq4[q];
            aw[q * 4 + 0] = t.x; aw[q * 4 + 1] = t.y;
            aw[q * 4 + 2] = t.z; aw[q * 4 + 3] = t.w;
        }
        const bool isacc = (d < 64);
#pragma unroll
        for (int cc = 0; cc < 12; ++cc) {
            unsigned int wb[8];
#pragma unroll
            for (int e = 0; e < 8; ++e) {
                const int j = cc * 8 + e;
                const int p = j / 6, rem = j % 6;
                float val;
                if (rem < 3) val = isacc ? aw[rem * 16 + p] : 0.0f;
                else         val = isacc ? 0.0f : aw[(rem - 3) * 16 + p];
                wb[e] = bfbits(val);
            }
            uint4 pk;
            pk.x = wb[0] | (wb[1] << 16);
            pk.y = wb[2] | (wb[3] << 16);
            pk.z = wb[4] | (wb[5] << 16);
            pk.w = wb[6] | (wb[7] << 16);
            Wl[d * 16 + (cc ^ (d & 7))] = pk;
        }
    }

    {
        const float* abase = in + (size_t)b * (TT * 6) + (size_t)sbase * 96;
#pragma unroll
        for (int it = 0; it < 3; ++it) {
            const int idx = it * 256 + tid;
            const int row = idx / 12;
            const int ch = idx % 12;
            const float* src = abase + row * 96 + ch * 8;
            const float4 t0 = *(const float4*)src;
            const float4 t1 = *(const float4*)(src + 4);
            uint4 pk;
            pk.x = bfbits(t0.x) | (bfbits(t0.y) << 16);
            pk.y = bfbits(t0.z) | (bfbits(t0.w) << 16);
            pk.z = bfbits(t1.x) | (bfbits(t1.y) << 16);
            pk.w = bfbits(t1.z) | (bfbits(t1.w) << 16);
            Al[row * 16 + (ch ^ (row & 7))] = pk;
        }
    }
    __syncthreads();

    const int wv = tid >> 6;
    const int lane = tid & 63;
    const int lrow = lane & 15;
    const int lk = lane >> 4;

    f32x4 acc[4][2] = {};
#pragma unroll
    for (int ks = 0; ks < 3; ++ks) {
        bf16x8 a[4], bf[2];
#pragma unroll
        for (int m = 0; m < 4; ++m) {
            const int row = m * 16 + lrow;
            a[m] = __builtin_bit_cast(bf16x8, Al[row * 16 + ((ks * 4 + lk) ^ (row & 7))]);
        }
#pragma unroll
        for (int n = 0; n < 2; ++n) {
            const int col = (wv * 2 + n) * 16 + lrow;
            bf[n] = __builtin_bit_cast(bf16x8, Wl[col * 16 + ((ks * 4 + lk) ^ (col & 7))]);
        }
#pragma unroll
        for (int m = 0; m < 4; ++m)
#pragma unroll
            for (int n = 0; n < 2; ++n)
                acc[m][n] = __builtin_amdgcn_mfma_f32_16x16x32_bf16(a[m], bf[n], acc[m][n], 0, 0, 0);
    }
    __syncthreads();  // GEMM done reading Wl/Al before xtile overlay

    ushort_t* xt16 = (ushort_t*)smem;
#pragma unroll
    for (int n = 0; n < 2; ++n) {
        const int col = (wv * 2 + n) * 16 + lrow;
        const float bv = (col < 64) ? acc_b[col] : gyro_b[col - 64];
#pragma unroll
        for (int m = 0; m < 4; ++m)
#pragma unroll
            for (int r = 0; r < 4; ++r) {
                const int row = m * 16 + lk * 4 + r;
                const float pe = pos_emb[(size_t)(sbase + row) * DD + col];
                const float xv = acc[m][n][r] + bv + pe;
                const __bf16 xb = (__bf16)xv;
                x[(size_t)(rbase + row) * DD + col] = xb;
                xt_store(xt16, row, col, __builtin_bit_cast(ushort_t, xb));
            }
    }
    __syncthreads();
    ln_pc1_tail<64>(smem, tid, lng, lnb, wpk1, pc1b, xcT, b, sbase >> 3);
}

// ---------------------------------------------------------------------------
// Kernel 2 (FUSED): conv + BN + silu + scan -> LDS -> pc2 GEMM + residual,
// then (TAIL) next-layer LN + pc1 from the freshly computed x tile.
// 32-position chunks (grid 32 x B), 16 KB LDS, forced <=64 VGPR for
// 8 blocks/CU (32 waves/CU). Params pre-folded in sparm[e][12].
// ---------------------------------------------------------------------------
template <int TAIL>
__global__ __launch_bounds__(256, 8) void k_scan_pc2(
    const __bf16* __restrict__ xcIn,    // [B][128][E][8]
    const ushort_t* __restrict__ wpk2_, // packed [8][8][64][8]
    const float* __restrict__ sparm,    // [E][12]
    const float* __restrict__ bias, __bf16* __restrict__ x,
    const float* __restrict__ lng, const float* __restrict__ lnb,
    const ushort_t* __restrict__ wpk1, const float* __restrict__ pc1b,
    __bf16* __restrict__ xcOut) {
    __shared__ __align__(16) char smem[16384];  // ym tile / xtile+A2 overlay

    const int tid = threadIdx.x;
    const int sc = blockIdx.x;      // 0..31
    const int b = blockIdx.y;

    // ---------------- phase 1: conv + BN + silu + scan -> LDS -------------
    {
        const int e = tid;
        const float4 p0 = *(const float4*)(sparm + (size_t)e * 12);
        const float4 p1 = *(const float4*)(sparm + (size_t)e * 12 + 4);
        const float Dv = sparm[(size_t)e * 12 + 8];
        const float d0 = p0.x, d1 = p0.y, d2 = p0.z, d3 = p0.w;
        const float d4 = p1.x, cbias = p1.y, Aexp = p1.z, cb = p1.w;

        const int sgbase = sc * 4 - 4;      // G[j] = granule sgbase + j
        const uint4* xq = (const uint4*)xcIn;
        uint4 G[9];
#pragma unroll
        for (int j = 0; j < 9; ++j) {
            const int sg = sgbase + j;
            G[j] = (sg >= 0 && sg < 128)
                       ? xq[((size_t)b * 128 + sg) * EE + e]
                       : make_uint4(0, 0, 0, 0);
        }

        __bf16* lbase = (__bf16*)smem;
        const int ehash = e >> 3;
        const int elow = e & 7;

        float g = 0.0f, pw6, pw7;
        if (sc != 0) {
            // 24-step warmup, no stores, no guards (attenuation e^-12).
            pw6 = bflow(G[0].w); pw7 = bfhigh(G[0].w);
#pragma unroll
            for (int j = 1; j <= 3; ++j) {
                float cw[8];
                cw[0] = bflow(G[j].x); cw[1] = bfhigh(G[j].x);
                cw[2] = bflow(G[j].y); cw[3] = bfhigh(G[j].y);
                cw[4] = bflow(G[j].z); cw[5] = bfhigh(G[j].z);
                cw[6] = bflow(G[j].w); cw[7] = bfhigh(G[j].w);
                const float nh0 = bflow(G[j + 1].x);
                const float nh1 = bfhigh(G[j + 1].x);
#pragma unroll
                for (int u = 0; u < 8; ++u) {
                    const float xm2 = (u >= 2) ? cw[u - 2] : (u == 0 ? pw6 : pw7);
                    const float xm1 = (u >= 1) ? cw[u - 1] : pw7;
                    const float x0 = cw[u];
                    const float xp1 = (u < 7) ? cw[u + 1] : nh0;
                    const float xp2 = (u < 6) ? cw[u + 2] : (u == 6 ? nh0 : nh1);
                    const float z = xm2 * d0 + xm1 * d1 + x0 * d2 + xp1 * d3 +
                                    xp2 * d4 + cbias;
                    g = fmaf(Aexp, g, silu_f(z));
                }
                pw6 = cw[6]; pw7 = cw[7];
            }
        } else {
            pw6 = 0.0f; pw7 = 0.0f;   // sc==0: s<0 inputs are zero-padded
        }

#pragma unroll
        for (int j = 4; j <= 7; ++j) {
            float cw[8];
            cw[0] = bflow(G[j].x); cw[1] = bfhigh(G[j].x);
            cw[2] = bflow(G[j].y); cw[3] = bfhigh(G[j].y);
            cw[4] = bflow(G[j].z); cw[5] = bfhigh(G[j].z);
            cw[6] = bflow(G[j].w); cw[7] = bfhigh(G[j].w);
            const float nh0 = bflow(G[j + 1].x);
            const float nh1 = bfhigh(G[j + 1].x);

            float aa[8];
#pragma unroll
            for (int u = 0; u < 8; ++u) {
                const float xm2 = (u >= 2) ? cw[u - 2] : (u == 0 ? pw6 : pw7);
                const float xm1 = (u >= 1) ? cw[u - 1] : pw7;
                const float x0 = cw[u];
                const float xp1 = (u < 7) ? cw[u + 1] : nh0;
                const float xp2 = (u < 6) ? cw[u + 2] : (u == 6 ? nh0 : nh1);
                const float z = xm2 * d0 + xm1 * d1 + x0 * d2 + xp1 * d3 +
                                xp2 * d4 + cbias;
                aa[u] = silu_f(z);
            }
#pragma unroll
            for (int u = 0; u < 8; ++u) {
                g = fmaf(Aexp, g, aa[u]);
                const int srel = (j - 4) * 8 + u;
                lbase[srel * 256 + ((ehash ^ (srel & 7)) << 3) + elow] =
                    (__bf16)(cb * g + Dv * aa[u]);
            }
            pw6 = cw[6]; pw7 = cw[7];
        }
    }
    __syncthreads();

    // ---------------- phase 2: pc2 GEMM + bias + residual -----------------
    const size_t rbase = ((size_t)b << 10) + ((size_t)sc << 5);
    const int wv = tid >> 6;
    const int lane = tid & 63;
    const int lrow = lane & 15;
    const int lk = lane >> 4;
    const uint4* wq = (const uint4*)wpk2_;
    const uint4* Albd = (const uint4*)smem;

    f32x4 acc[2][2] = {};
    for (int ks = 0; ks < 8; ++ks) {
        bf16x8 a[2], bfr[2];
#pragma unroll
        for (int m = 0; m < 2; ++m) {
            const int idx = ((lrow + m * 16) * 32 + ks * 4 + lk) ^ (lrow & 7);
            a[m] = __builtin_bit_cast(bf16x8, Albd[idx]);
        }
#pragma unroll
        for (int n = 0; n < 2; ++n) {
            const int nf = wv * 2 + n;
            bfr[n] = __builtin_bit_cast(bf16x8, wq[(ks * 8 + nf) * 64 + lane]);
        }
#pragma unroll
        for (int m = 0; m < 2; ++m)
#pragma unroll
            for (int n = 0; n < 2; ++n)
                acc[m][n] = __builtin_amdgcn_mfma_f32_16x16x32_bf16(a[m], bfr[n], acc[m][n], 0, 0, 0);
    }
    if constexpr (TAIL) __syncthreads();  // done reading ym before xtile overlay

    ushort_t* xt16 = (ushort_t*)smem;
#pragma unroll
    for (int n = 0; n < 2; ++n) {
        const int col = wv * 32 + n * 16 + lrow;
        const float bv = bias[col];
#pragma unroll
        for (int m = 0; m < 2; ++m)
#pragma unroll
            for (int r = 0; r < 4; ++r) {
                const int row = m * 16 + lk * 4 + r;
                __bf16* xp = x + (rbase + row) * DD + col;
                const float xn = (float)*xp + acc[m][n][r] + bv;
                const __bf16 xb = (__bf16)xn;
                *xp = xb;
                if constexpr (TAIL)
                    xt_store(xt16, row, col, __builtin_bit_cast(ushort_t, xb));
            }
    }
    if constexpr (TAIL) {
        __syncthreads();
        ln_pc1_tail<32>(smem, tid, lng, lnb, wpk1, pc1b, xcOut, b, sc * 4);
    }
}

// ---------------------------------------------------------------------------
// Final LN partial sums over 128-row chunks (x bf16).
// ---------------------------------------------------------------------------
__global__ __launch_bounds__(256) void k_finln_s1(
    const __bf16* __restrict__ x, float* __restrict__ partial) {
    const int chunk = blockIdx.x;
    const int b = blockIdx.y;
    const int tid = threadIdx.x;
    const int wv = tid >> 6;
    const int lane = tid & 63;
    const __bf16* xb = x + ((size_t)b * SS + chunk * 128) * DD;

    float a0 = 0.0f, a1 = 0.0f;
    for (int s = wv; s < 128; s += 4) {
        const unsigned int vv = *(const unsigned int*)(xb + (size_t)s * DD + lane * 2);
        const float vx = bflow(vv);
        const float vy = bfhigh(vv);
        float s1 = vx + vy;
        float s2 = vx * vx + vy * vy;
#pragma unroll
        for (int m = 1; m <= 32; m <<= 1) {
            s1 += __shfl_xor(s1, m);
            s2 += __shfl_xor(s2, m);
        }
        const float mean = s1 * (1.0f / 128.0f);
        const float rstd = rsqrtf(s2 * (1.0f / 128.0f) - mean * mean + EPSV);
        a0 += (vx - mean) * rstd;
        a1 += (vy - mean) * rstd;
    }
    __shared__ float red[4][128];
    red[wv][lane * 2] = a0;
    red[wv][lane * 2 + 1] = a1;
    __syncthreads();
    if (tid < 128) {
        partial[((size_t)b * 8 + chunk) * 128 + tid] =
            red[0][tid] + red[1][tid] + red[2][tid] + red[3][tid];
    }
}

// ---------------------------------------------------------------------------
// Head (finln stage-2 fused in) + softmax. Block per b.
// ---------------------------------------------------------------------------
__global__ __launch_bounds__(256) void k_head(
    const float* __restrict__ partial, const float* __restrict__ fg,
    const float* __restrict__ fb, const float* __restrict__ hw1,
    const float* __restrict__ hb1, const float* __restrict__ hw2,
    const float* __restrict__ hb2, float* __restrict__ out) {
    const int b = blockIdx.x;
    const int tid = threadIdx.x;
    __shared__ float xmb[128];
    __shared__ float hh[256];
    __shared__ float lg[18];
    __shared__ float eg[18];

    if (tid < 128) {
        float s = 0.0f;
#pragma unroll
        for (int c = 0; c < 8; ++c)
            s += partial[((size_t)b * 8 + c) * 128 + tid];
        xmb[tid] = fg[tid] * (s * (1.0f / (float)SS)) + fb[tid];
    }
    __syncthreads();

    float z = hb1[tid];
    for (int k = 0; k < 128; ++k) z += xmb[k] * hw1[k * 256 + tid];
    hh[tid] = z / (1.0f + expf(-z));
    __syncthreads();

    if (tid < NCLS) {
        float a = hb2[tid];
        for (int k = 0; k < 256; ++k) a += hh[k] * hw2[k * NCLS + tid];
        lg[tid] = a;
    }
    __syncthreads();
    if (tid < NCLS) {
        float m = lg[0];
        for (int j = 1; j < NCLS; ++j) m = fmaxf(m, lg[j]);
        eg[tid] = expf(lg[tid] - m);
    }
    __syncthreads();
    if (tid < NCLS) {
        float ssum = 0.0f;
        for (int j = 0; j < NCLS; ++j) ssum += eg[j];
        out[b * NCLS + tid] = eg[tid] / ssum;
    }
}

// ---------------------------------------------------------------------------
extern "C" void kernel_launch(void* const* d_in, const int* in_sizes, int n_in,
                              void* d_out, int out_size, void* d_ws, size_t ws_size,
                              hipStream_t stream) {
    const float* inputs  = (const float*)d_in[0];
    const float* acc_w   = (const float*)d_in[1];
    const float* acc_b   = (const float*)d_in[2];
    const float* gyro_w  = (const float*)d_in[3];
    const float* gyro_b  = (const float*)d_in[4];
    const float* pos_emb = (const float*)d_in[5];
    const float* ln_g    = (const float*)d_in[6];
    const float* ln_b    = (const float*)d_in[7];
    const float* pc1_w   = (const float*)d_in[8];
    const float* pc1_b   = (const float*)d_in[9];
    const float* dw_w    = (const float*)d_in[10];
    const float* dw_b    = (const float*)d_in[11];
    const float* bn_g    = (const float*)d_in[12];
    const float* bn_b    = (const float*)d_in[13];
    const float* bn_mean = (const float*)d_in[14];
    const float* bn_var  = (const float*)d_in[15];
    const float* Ap      = (const float*)d_in[16];
    const float* Bp      = (const float*)d_in[17];
    const float* Cp      = (const float*)d_in[18];
    const float* Dp      = (const float*)d_in[19];
    const float* pc2_w   = (const float*)d_in[20];
    const float* pc2_b   = (const float*)d_in[21];
    const float* fln_g   = (const float*)d_in[22];
    const float* fln_b   = (const float*)d_in[23];
    const float* hw1     = (const float*)d_in[24];
    const float* hb1     = (const float*)d_in[25];
    const float* hw2     = (const float*)d_in[26];
    const float* hb2     = (const float*)d_in[27];

    const size_t nx  = (size_t)BB * SS * DD;   // 8388608
    const size_t nxc = (size_t)BB * SS * EE;   // 16777216

    ushort_t* wsu = (ushort_t*)d_ws;
    ushort_t* xb   = wsu;                       // bf16 x [M,128]
    ushort_t* xc0  = xb + nx;                   // bf16 xcT ping
    ushort_t* xc1  = xc0 + nxc;                 // bf16 xcT pong
    ushort_t* wpk1 = xc1 + nxc;
    ushort_t* wpk2 = wpk1 + 3 * 32768;
    float* sparm   = (float*)(wpk2 + 3 * 32768);  // [3][256][12]
    float* partial = sparm + 3 * 256 * 12;

    __bf16* x    = (__bf16*)xb;
    __bf16* xcT0 = (__bf16*)xc0;
    __bf16* xcT1 = (__bf16*)xc1;

    k_pack<<<99, 256, 0, stream>>>(pc1_w, pc2_w, dw_w, dw_b, bn_g, bn_b,
                                   bn_mean, bn_var, Ap, Bp, Cp, Dp,
                                   wpk1, wpk2, sparm);

    // stem + layer-0 LN/pc1 tail -> xcT0
    k_stem_mfma<<<1024, 256, 0, stream>>>(inputs, acc_w, acc_b, gyro_w, gyro_b,
                                          pos_emb, x,
                                          ln_g, ln_b, wpk1, pc1_b, xcT0);

    // layer 0: reads xcT0, tail writes layer-1 xcT1
    k_scan_pc2<1><<<dim3(32, BB), 256, 0, stream>>>(
        xcT0, wpk2, sparm,
        pc2_b, x,
        ln_g + DD, ln_b + DD, wpk1 + 32768, pc1_b + EE, xcT1);

    // layer 1: reads xcT1, tail writes layer-2 xcT0
    k_scan_pc2<1><<<dim3(32, BB), 256, 0, stream>>>(
        xcT1, wpk2 + 32768, sparm + 256 * 12,
        pc2_b + DD, x,
        ln_g + 2 * DD, ln_b + 2 * DD, wpk1 + 2 * 32768, pc1_b + 2 * EE, xcT0);

    // layer 2: reads xcT0, no tail
    k_scan_pc2<0><<<dim3(32, BB), 256, 0, stream>>>(
        xcT0, wpk2 + 2 * 32768, sparm + 2 * 256 * 12,
        pc2_b + 2 * DD, x,
        nullptr, nullptr, nullptr, nullptr, nullptr);

    k_finln_s1<<<dim3(8, BB), 256, 0, stream>>>(x, partial);
    k_head<<<BB, 256, 0, stream>>>(partial, fln_g, fln_b, hw1, hb1, hw2, hb2,
                                   (float*)d_out);
}

// Round 3
// 153.845 us; speedup vs baseline: 1.1850x; 1.0360x over previous
//
#include <hip/hip_runtime.h>
#include <hip/hip_bf16.h>

// Problem constants
#define BB 64
#define TT 16384
#define DD 128
#define EE 256
#define NN 8
#define SS 1024
#define NCLS 18
#define NBLK 3
#define EPSV 1e-5f

typedef __bf16 bf16x8 __attribute__((ext_vector_type(8)));
typedef __bf16 bf16x4 __attribute__((ext_vector_type(4)));
typedef float f32x4 __attribute__((ext_vector_type(4)));
typedef unsigned short ushort_t;

__device__ __forceinline__ float silu_f(float z) {
    return z * __builtin_amdgcn_rcpf(1.0f + __expf(-z));
}
__device__ __forceinline__ unsigned int bfbits(float v) {
    return (unsigned int)__builtin_bit_cast(unsigned short, (__bf16)v);
}
__device__ __forceinline__ float bflow(unsigned int u) {
    return (float)__builtin_bit_cast(__bf16, (unsigned short)(u & 0xffffu));
}
__device__ __forceinline__ float bfhigh(unsigned int u) {
    return (float)__builtin_bit_cast(__bf16, (unsigned short)(u >> 16));
}

// ---------------------------------------------------------------------------
// Merged pack: pc1_w -> wpk1[L][ks4][nf16][lane64][e8]
//              pc2_w -> wpk2[L][ks8][nf8][lane64][e8]
//              scan params -> sparm[L][e][12] = {d0..d3, d4,cbias,Aexp,cb, Dv}
// ---------------------------------------------------------------------------
__global__ __launch_bounds__(256) void k_pack(
    const float* __restrict__ w1, const float* __restrict__ w2,
    const float* __restrict__ dw_w, const float* __restrict__ dw_b,
    const float* __restrict__ bn_g, const float* __restrict__ bn_b,
    const float* __restrict__ bn_mean, const float* __restrict__ bn_var,
    const float* __restrict__ Ap, const float* __restrict__ Bp,
    const float* __restrict__ Cp, const float* __restrict__ Dp,
    ushort_t* __restrict__ wpk1, ushort_t* __restrict__ wpk2,
    float* __restrict__ sparm) {
    const int t0 = blockIdx.x * 256 + threadIdx.x;
    if (t0 >= 24576) {
        const int t = t0 - 24576;
        if (t >= 768) return;
        const int le = t;  // L*256+e
        const float scale = bn_g[le] * rsqrtf(bn_var[le] + EPSV);
        float cb = 0.0f;
#pragma unroll
        for (int n = 0; n < 8; ++n) cb += Cp[le * 8 + n] * Bp[le * 8 + n];
        float* dst = sparm + (size_t)le * 12;
        dst[0] = dw_w[le * 5 + 0] * scale;
        dst[1] = dw_w[le * 5 + 1] * scale;
        dst[2] = dw_w[le * 5 + 2] * scale;
        dst[3] = dw_w[le * 5 + 3] * scale;
        dst[4] = dw_w[le * 5 + 4] * scale;
        dst[5] = (dw_b[le] - bn_mean[le]) * scale + bn_b[le];
        dst[6] = __expf(Ap[le]);
        dst[7] = cb;
        dst[8] = Dp[le];
        dst[9] = 0.0f; dst[10] = 0.0f; dst[11] = 0.0f;
        return;
    }
    const float* src;
    uint4* dst;
    if (t0 < 12288) {
        const int L = t0 >> 12;
        const int r = t0 & 4095;
        const int ks = r >> 10;
        const int r2 = r & 1023;
        const int nf = r2 >> 6;
        const int lane = r2 & 63;
        const int col = nf * 16 + (lane & 15);
        const int k0 = ks * 32 + (lane >> 4) * 8;
        src = w1 + ((size_t)L * EE + col) * DD + k0;
        dst = (uint4*)wpk1 + t0;
    } else {
        const int t = t0 - 12288;
        const int L = t >> 12;
        const int r = t & 4095;
        const int ks = r >> 9;
        const int r2 = r & 511;
        const int nf = r2 >> 6;
        const int lane = r2 & 63;
        const int col = nf * 16 + (lane & 15);
        const int k0 = ks * 32 + (lane >> 4) * 8;
        src = w2 + ((size_t)L * DD + col) * EE + k0;
        dst = (uint4*)wpk2 + t;
    }
    const float4 a = ((const float4*)src)[0];
    const float4 b = ((const float4*)src)[1];
    bf16x8 pk;
    pk[0] = (__bf16)a.x; pk[1] = (__bf16)a.y; pk[2] = (__bf16)a.z; pk[3] = (__bf16)a.w;
    pk[4] = (__bf16)b.x; pk[5] = (__bf16)b.y; pk[6] = (__bf16)b.z; pk[7] = (__bf16)b.w;
    *dst = __builtin_bit_cast(uint4, pk);
}

// ---------------------------------------------------------------------------
// Shared tail: LN + pc1 GEMM + silu -> xcT granules, fed from an LDS x-tile.
// xtile: bf16 [MROWS][128], 16B-chunk XOR swizzle:
//   ushort idx = row*128 + (((col>>3) ^ (row&7))<<3) + (col&7)
// A2 region at smem + MROWS*256 bytes: uint4[MROWS*16], pc1 A-swizzle.
// NT threads; wave grid (NT/256) x 4 over (rows, cols).
// ---------------------------------------------------------------------------
__device__ __forceinline__ void xt_store(ushort_t* xt16, int row, int col,
                                         ushort_t val) {
    xt16[row * 128 + (((col >> 3) ^ (row & 7)) << 3) + (col & 7)] = val;
}

template <int MROWS, int NT>
__device__ __forceinline__ void ln_pc1_tail(
    char* smem, const int tid,
    const float* __restrict__ lng, const float* __restrict__ lnb,
    const ushort_t* __restrict__ wpk, const float* __restrict__ bias1,
    __bf16* __restrict__ xcT, const int bidx, const int sg0) {
    constexpr int TPR = NT / MROWS;   // threads per row: 4
    constexpr int CPT = 16 / TPR;     // 16B chunks per thread: 4
    const uint4* xt = (const uint4*)smem;              // [MROWS][16] swizzled
    uint4* A2 = (uint4*)(smem + MROWS * 256);          // [MROWS*16]

    {
        const int row = tid / TPR;
        const int q = tid % TPR;
        float v[CPT * 8];
#pragma unroll
        for (int i = 0; i < CPT; ++i) {
            const uint4 tv4 = xt[row * 16 + ((q * CPT + i) ^ (row & 7))];
            const bf16x8 tv = __builtin_bit_cast(bf16x8, tv4);
#pragma unroll
            for (int e2 = 0; e2 < 8; ++e2) v[i * 8 + e2] = (float)tv[e2];
        }
        float s1 = 0.0f, s2 = 0.0f;
#pragma unroll
        for (int i = 0; i < CPT * 8; ++i) { s1 += v[i]; s2 += v[i] * v[i]; }
        s1 += __shfl_xor(s1, 1); s2 += __shfl_xor(s2, 1);
        s1 += __shfl_xor(s1, 2); s2 += __shfl_xor(s2, 2);
        const float mean = s1 * (1.0f / 128.0f);
        const float rstd = rsqrtf(s2 * (1.0f / 128.0f) - mean * mean + EPSV);
        const float4* gp4 = (const float4*)lng;
        const float4* bp4 = (const float4*)lnb;
#pragma unroll
        for (int c = 0; c < CPT; ++c) {
            const int ci = q * CPT + c;
            float4 g0 = gp4[ci * 2], g1 = gp4[ci * 2 + 1];
            float4 b0 = bp4[ci * 2], b1 = bp4[ci * 2 + 1];
            const float gg[8] = {g0.x, g0.y, g0.z, g0.w, g1.x, g1.y, g1.z, g1.w};
            const float bb2[8] = {b0.x, b0.y, b0.z, b0.w, b1.x, b1.y, b1.z, b1.w};
            bf16x8 pk;
#pragma unroll
            for (int e2 = 0; e2 < 8; ++e2)
                pk[e2] = (__bf16)((v[c * 8 + e2] - mean) * rstd * gg[e2] + bb2[e2]);
            A2[(row * 16 + ci) ^ (row & 7)] = __builtin_bit_cast(uint4, pk);
        }
    }
    __syncthreads();

    const int wv = tid >> 6;
    const int wr = wv >> 2;           // 0 for NT=256
    const int wc = wv & 3;
    const int lane = tid & 63;
    const int lrow = lane & 15;
    const int lk = lane >> 4;
    const uint4* wq = (const uint4*)wpk;

    f32x4 acc[4][4] = {};
    for (int ks = 0; ks < 4; ++ks) {
        bf16x8 av[4], bw[4];
#pragma unroll
        for (int m = 0; m < 4; ++m) {
            const int row = wr * 64 + m * 16 + lrow;
            const int idx = (row * 16 + ks * 4 + lk) ^ (row & 7);
            av[m] = __builtin_bit_cast(bf16x8, A2[idx]);
        }
#pragma unroll
        for (int n = 0; n < 4; ++n) {
            const int nf = wc * 4 + n;
            bw[n] = __builtin_bit_cast(bf16x8, wq[(ks * 16 + nf) * 64 + lane]);
        }
#pragma unroll
        for (int m = 0; m < 4; ++m)
#pragma unroll
            for (int n = 0; n < 4; ++n)
                acc[m][n] = __builtin_amdgcn_mfma_f32_16x16x32_bf16(av[m], bw[n], acc[m][n], 0, 0, 0);
    }

#pragma unroll
    for (int n = 0; n < 4; ++n) {
        const int col = wc * 64 + n * 16 + lrow;
        const float bv = bias1[col];
#pragma unroll
        for (int m = 0; m < 4; ++m) {
            bf16x4 pk;
#pragma unroll
            for (int r = 0; r < 4; ++r)
                pk[r] = (__bf16)silu_f(acc[m][n][r] + bv);
            const int sg = sg0 + wr * 8 + m * 2 + (lk >> 1);
            __bf16* dst = xcT + ((((size_t)bidx * 128 + sg) * EE + col) << 3) +
                          (lk & 1) * 4;
            *(bf16x4*)dst = pk;
        }
    }
}

// ---------------------------------------------------------------------------
// Kernel 1: stem MFMA GEMM, fused with layer-0 LN+pc1 tail (64-row tiles).
// ---------------------------------------------------------------------------
__global__ __launch_bounds__(256) void k_stem_mfma(
    const float* __restrict__ in, const float* __restrict__ acc_w,
    const float* __restrict__ acc_b, const float* __restrict__ gyro_w,
    const float* __restrict__ gyro_b, const float* __restrict__ pos_emb,
    __bf16* __restrict__ x,
    const float* __restrict__ lng, const float* __restrict__ lnb,
    const ushort_t* __restrict__ wpk1, const float* __restrict__ pc1b,
    __bf16* __restrict__ xcT) {
    __shared__ __align__(16) char smem[49152];
    uint4* Wl = (uint4*)smem;             // 128*16 uint4 = 32 KB
    uint4* Al = (uint4*)(smem + 32768);   // 64*16 uint4 = 16 KB

    const int tid = threadIdx.x;
    const int rbase = blockIdx.x * 64;
    const int b = rbase >> 10;
    const int sbase = rbase & 1023;

    if (tid < 128) {
        const int d = tid;
        const float* wsrc = (d < 64) ? (acc_w + d * 48) : (gyro_w + (d - 64) * 48);
        float aw[48];
        const float4* wq4 = (const float4*)wsrc;
#pragma unroll
        for (int q = 0; q < 12; ++q) {
            float4 t = wq4[q];
            aw[q * 4 + 0] = t.x; aw[q * 4 + 1] = t.y;
            aw[q * 4 + 2] = t.z; aw[q * 4 + 3] = t.w;
        }
        const bool isacc = (d < 64);
#pragma unroll
        for (int cc = 0; cc < 12; ++cc) {
            unsigned int wb[8];
#pragma unroll
            for (int e = 0; e < 8; ++e) {
                const int j = cc * 8 + e;
                const int p = j / 6, rem = j % 6;
                float val;
                if (rem < 3) val = isacc ? aw[rem * 16 + p] : 0.0f;
                else         val = isacc ? 0.0f : aw[(rem - 3) * 16 + p];
                wb[e] = bfbits(val);
            }
            uint4 pk;
            pk.x = wb[0] | (wb[1] << 16);
            pk.y = wb[2] | (wb[3] << 16);
            pk.z = wb[4] | (wb[5] << 16);
            pk.w = wb[6] | (wb[7] << 16);
            Wl[d * 16 + (cc ^ (d & 7))] = pk;
        }
    }

    {
        const float* abase = in + (size_t)b * (TT * 6) + (size_t)sbase * 96;
#pragma unroll
        for (int it = 0; it < 3; ++it) {
            const int idx = it * 256 + tid;
            const int row = idx / 12;
            const int ch = idx % 12;
            const float* src = abase + row * 96 + ch * 8;
            const float4 t0 = *(const float4*)src;
            const float4 t1 = *(const float4*)(src + 4);
            uint4 pk;
            pk.x = bfbits(t0.x) | (bfbits(t0.y) << 16);
            pk.y = bfbits(t0.z) | (bfbits(t0.w) << 16);
            pk.z = bfbits(t1.x) | (bfbits(t1.y) << 16);
            pk.w = bfbits(t1.z) | (bfbits(t1.w) << 16);
            Al[row * 16 + (ch ^ (row & 7))] = pk;
        }
    }
    __syncthreads();

    const int wv = tid >> 6;
    const int lane = tid & 63;
    const int lrow = lane & 15;
    const int lk = lane >> 4;

    f32x4 acc[4][2] = {};
#pragma unroll
    for (int ks = 0; ks < 3; ++ks) {
        bf16x8 a[4], bf[2];
#pragma unroll
        for (int m = 0; m < 4; ++m) {
            const int row = m * 16 + lrow;
            a[m] = __builtin_bit_cast(bf16x8, Al[row * 16 + ((ks * 4 + lk) ^ (row & 7))]);
        }
#pragma unroll
        for (int n = 0; n < 2; ++n) {
            const int col = (wv * 2 + n) * 16 + lrow;
            bf[n] = __builtin_bit_cast(bf16x8, Wl[col * 16 + ((ks * 4 + lk) ^ (col & 7))]);
        }
#pragma unroll
        for (int m = 0; m < 4; ++m)
#pragma unroll
            for (int n = 0; n < 2; ++n)
                acc[m][n] = __builtin_amdgcn_mfma_f32_16x16x32_bf16(a[m], bf[n], acc[m][n], 0, 0, 0);
    }
    __syncthreads();  // GEMM done reading Wl/Al before xtile overlay

    ushort_t* xt16 = (ushort_t*)smem;
#pragma unroll
    for (int n = 0; n < 2; ++n) {
        const int col = (wv * 2 + n) * 16 + lrow;
        const float bv = (col < 64) ? acc_b[col] : gyro_b[col - 64];
#pragma unroll
        for (int m = 0; m < 4; ++m)
#pragma unroll
            for (int r = 0; r < 4; ++r) {
                const int row = m * 16 + lk * 4 + r;
                const float pe = pos_emb[(size_t)(sbase + row) * DD + col];
                const float xv = acc[m][n][r] + bv + pe;
                const __bf16 xb = (__bf16)xv;
                x[(size_t)(rbase + row) * DD + col] = xb;
                xt_store(xt16, row, col, __builtin_bit_cast(ushort_t, xb));
            }
    }
    __syncthreads();
    ln_pc1_tail<64, 256>(smem, tid, lng, lnb, wpk1, pc1b, xcT, b, sbase >> 3);
}

// ---------------------------------------------------------------------------
// Kernel 2 (FUSED): conv + BN + silu + scan -> LDS -> pc2 GEMM + residual,
// then (TAIL) next-layer LN + pc1 from the freshly computed x tile.
// 512-thread blocks; each 4-wave half processes one 64-position sub-chunk
// (24-step warmup each). Grid 8 x B -> 512 blocks, 2 blocks/CU, 16 waves/CU,
// 128-VGPR budget so the 13 staged granules stay resident.
// ---------------------------------------------------------------------------
template <int TAIL>
__global__ __launch_bounds__(512, 4) void k_scan_pc2(
    const __bf16* __restrict__ xcIn,    // [B][128][E][8]
    const ushort_t* __restrict__ wpk2_, // packed [8][8][64][8]
    const float* __restrict__ sparm,    // [E][12]
    const float* __restrict__ bias, __bf16* __restrict__ x,
    const float* __restrict__ lng, const float* __restrict__ lnb,
    const ushort_t* __restrict__ wpk1, const float* __restrict__ pc1b,
    __bf16* __restrict__ xcOut) {
    __shared__ __align__(16) char smem[65536];  // y tile / xtile+A2 overlay

    const int tid = threadIdx.x;
    const int sc = blockIdx.x;      // 0..7
    const int b = blockIdx.y;

    // ---------------- phase 1: conv + BN + silu + scan -> LDS -------------
    {
        const int e = tid & 255;
        const int sub = tid >> 8;           // 0/1: which 64-pos sub-chunk
        const int sce = sc * 2 + sub;       // 0..15
        const float4 p0 = *(const float4*)(sparm + (size_t)e * 12);
        const float4 p1 = *(const float4*)(sparm + (size_t)e * 12 + 4);
        const float Dv = sparm[(size_t)e * 12 + 8];
        const float d0 = p0.x, d1 = p0.y, d2 = p0.z, d3 = p0.w;
        const float d4 = p1.x, cbias = p1.y, Aexp = p1.z, cb = p1.w;

        const int sgbase = sce * 8 - 4;     // G[j] = granule sgbase + j
        const uint4* xq = (const uint4*)xcIn + ((size_t)b * 128 + sgbase) * EE + e;
        uint4 G[13];
#pragma unroll
        for (int j = 0; j < 13; ++j) {
            const int sg = sgbase + j;
            G[j] = (sg >= 0 && sg < 128) ? xq[j * EE] : make_uint4(0, 0, 0, 0);
        }

        __bf16* lbase = (__bf16*)smem;
        const int ehash = e >> 3;
        const int elow = e & 7;
        const int rowoff = sub * 64;

        float g = 0.0f, pw6, pw7;
        if (sce != 0) {
            // 24-step warmup, no stores, no guards (attenuation e^-12).
            pw6 = bflow(G[0].w); pw7 = bfhigh(G[0].w);
#pragma unroll
            for (int j = 1; j <= 3; ++j) {
                float cw[8];
                cw[0] = bflow(G[j].x); cw[1] = bfhigh(G[j].x);
                cw[2] = bflow(G[j].y); cw[3] = bfhigh(G[j].y);
                cw[4] = bflow(G[j].z); cw[5] = bfhigh(G[j].z);
                cw[6] = bflow(G[j].w); cw[7] = bfhigh(G[j].w);
                const float nh0 = bflow(G[j + 1].x);
                const float nh1 = bfhigh(G[j + 1].x);
#pragma unroll
                for (int u = 0; u < 8; ++u) {
                    const float xm2 = (u >= 2) ? cw[u - 2] : (u == 0 ? pw6 : pw7);
                    const float xm1 = (u >= 1) ? cw[u - 1] : pw7;
                    const float x0 = cw[u];
                    const float xp1 = (u < 7) ? cw[u + 1] : nh0;
                    const float xp2 = (u < 6) ? cw[u + 2] : (u == 6 ? nh0 : nh1);
                    const float z = xm2 * d0 + xm1 * d1 + x0 * d2 + xp1 * d3 +
                                    xp2 * d4 + cbias;
                    g = fmaf(Aexp, g, silu_f(z));
                }
                pw6 = cw[6]; pw7 = cw[7];
            }
        } else {
            pw6 = 0.0f; pw7 = 0.0f;   // sce==0: s<0 inputs are zero-padded
        }

#pragma unroll
        for (int j = 4; j <= 11; ++j) {
            float cw[8];
            cw[0] = bflow(G[j].x); cw[1] = bfhigh(G[j].x);
            cw[2] = bflow(G[j].y); cw[3] = bfhigh(G[j].y);
            cw[4] = bflow(G[j].z); cw[5] = bfhigh(G[j].z);
            cw[6] = bflow(G[j].w); cw[7] = bfhigh(G[j].w);
            const float nh0 = bflow(G[j + 1].x);
            const float nh1 = bfhigh(G[j + 1].x);

            float aa[8];
#pragma unroll
            for (int u = 0; u < 8; ++u) {
                const float xm2 = (u >= 2) ? cw[u - 2] : (u == 0 ? pw6 : pw7);
                const float xm1 = (u >= 1) ? cw[u - 1] : pw7;
                const float x0 = cw[u];
                const float xp1 = (u < 7) ? cw[u + 1] : nh0;
                const float xp2 = (u < 6) ? cw[u + 2] : (u == 6 ? nh0 : nh1);
                const float z = xm2 * d0 + xm1 * d1 + x0 * d2 + xp1 * d3 +
                                xp2 * d4 + cbias;
                aa[u] = silu_f(z);
            }
#pragma unroll
            for (int u = 0; u < 8; ++u) {
                g = fmaf(Aexp, g, aa[u]);
                const int r = rowoff + (j - 4) * 8 + u;
                lbase[r * 256 + ((ehash ^ (r & 7)) << 3) + elow] =
                    (__bf16)(cb * g + Dv * aa[u]);
            }
            pw6 = cw[6]; pw7 = cw[7];
        }
    }
    __syncthreads();

    // ---------------- phase 2: pc2 GEMM (128 rows) + bias + residual ------
    const size_t rbase = ((size_t)b << 10) + ((size_t)sc << 7);
    const int wv = tid >> 6;
    const int wr = wv >> 2;   // 2 row groups of 64
    const int wc = wv & 3;    // 4 col groups of 32
    const int lane = tid & 63;
    const int lrow = lane & 15;
    const int lk = lane >> 4;
    const uint4* wq = (const uint4*)wpk2_;
    const uint4* Albd = (const uint4*)smem;

    f32x4 acc[4][2] = {};
    for (int ks = 0; ks < 8; ++ks) {
        bf16x8 a[4], bfr[2];
#pragma unroll
        for (int m = 0; m < 4; ++m) {
            const int row = wr * 64 + m * 16 + lrow;
            const int idx = (row * 32 + ks * 4 + lk) ^ (row & 7);
            a[m] = __builtin_bit_cast(bf16x8, Albd[idx]);
        }
#pragma unroll
        for (int n = 0; n < 2; ++n) {
            const int nf = wc * 2 + n;
            bfr[n] = __builtin_bit_cast(bf16x8, wq[(ks * 8 + nf) * 64 + lane]);
        }
#pragma unroll
        for (int m = 0; m < 4; ++m)
#pragma unroll
            for (int n = 0; n < 2; ++n)
                acc[m][n] = __builtin_amdgcn_mfma_f32_16x16x32_bf16(a[m], bfr[n], acc[m][n], 0, 0, 0);
    }
    if constexpr (TAIL) __syncthreads();  // done reading y before xtile overlay

    ushort_t* xt16 = (ushort_t*)smem;
#pragma unroll
    for (int n = 0; n < 2; ++n) {
        const int col = wc * 32 + n * 16 + lrow;
        const float bv = bias[col];
#pragma unroll
        for (int m = 0; m < 4; ++m)
#pragma unroll
            for (int r = 0; r < 4; ++r) {
                const int row = wr * 64 + m * 16 + lk * 4 + r;
                __bf16* xp = x + (rbase + row) * DD + col;
                const float xn = (float)*xp + acc[m][n][r] + bv;
                const __bf16 xb = (__bf16)xn;
                *xp = xb;
                if constexpr (TAIL)
                    xt_store(xt16, row, col, __builtin_bit_cast(ushort_t, xb));
            }
    }
    if constexpr (TAIL) {
        __syncthreads();
        ln_pc1_tail<128, 512>(smem, tid, lng, lnb, wpk1, pc1b, xcOut, b, sc * 16);
    }
}

// ---------------------------------------------------------------------------
// Final LN partial sums over 128-row chunks (x bf16).
// ---------------------------------------------------------------------------
__global__ __launch_bounds__(256) void k_finln_s1(
    const __bf16* __restrict__ x, float* __restrict__ partial) {
    const int chunk = blockIdx.x;
    const int b = blockIdx.y;
    const int tid = threadIdx.x;
    const int wv = tid >> 6;
    const int lane = tid & 63;
    const __bf16* xb = x + ((size_t)b * SS + chunk * 128) * DD;

    float a0 = 0.0f, a1 = 0.0f;
    for (int s = wv; s < 128; s += 4) {
        const unsigned int vv = *(const unsigned int*)(xb + (size_t)s * DD + lane * 2);
        const float vx = bflow(vv);
        const float vy = bfhigh(vv);
        float s1 = vx + vy;
        float s2 = vx * vx + vy * vy;
#pragma unroll
        for (int m = 1; m <= 32; m <<= 1) {
            s1 += __shfl_xor(s1, m);
            s2 += __shfl_xor(s2, m);
        }
        const float mean = s1 * (1.0f / 128.0f);
        const float rstd = rsqrtf(s2 * (1.0f / 128.0f) - mean * mean + EPSV);
        a0 += (vx - mean) * rstd;
        a1 += (vy - mean) * rstd;
    }
    __shared__ float red[4][128];
    red[wv][lane * 2] = a0;
    red[wv][lane * 2 + 1] = a1;
    __syncthreads();
    if (tid < 128) {
        partial[((size_t)b * 8 + chunk) * 128 + tid] =
            red[0][tid] + red[1][tid] + red[2][tid] + red[3][tid];
    }
}

// ---------------------------------------------------------------------------
// Head (finln stage-2 fused in) + softmax. Block per b.
// ---------------------------------------------------------------------------
__global__ __launch_bounds__(256) void k_head(
    const float* __restrict__ partial, const float* __restrict__ fg,
    const float* __restrict__ fb, const float* __restrict__ hw1,
    const float* __restrict__ hb1, const float* __restrict__ hw2,
    const float* __restrict__ hb2, float* __restrict__ out) {
    const int b = blockIdx.x;
    const int tid = threadIdx.x;
    __shared__ float xmb[128];
    __shared__ float hh[256];
    __shared__ float lg[18];
    __shared__ float eg[18];

    if (tid < 128) {
        float s = 0.0f;
#pragma unroll
        for (int c = 0; c < 8; ++c)
            s += partial[((size_t)b * 8 + c) * 128 + tid];
        xmb[tid] = fg[tid] * (s * (1.0f / (float)SS)) + fb[tid];
    }
    __syncthreads();

    float z = hb1[tid];
    for (int k = 0; k < 128; ++k) z += xmb[k] * hw1[k * 256 + tid];
    hh[tid] = z / (1.0f + expf(-z));
    __syncthreads();

    if (tid < NCLS) {
        float a = hb2[tid];
        for (int k = 0; k < 256; ++k) a += hh[k] * hw2[k * NCLS + tid];
        lg[tid] = a;
    }
    __syncthreads();
    if (tid < NCLS) {
        float m = lg[0];
        for (int j = 1; j < NCLS; ++j) m = fmaxf(m, lg[j]);
        eg[tid] = expf(lg[tid] - m);
    }
    __syncthreads();
    if (tid < NCLS) {
        float ssum = 0.0f;
        for (int j = 0; j < NCLS; ++j) ssum += eg[j];
        out[b * NCLS + tid] = eg[tid] / ssum;
    }
}

// ---------------------------------------------------------------------------
extern "C" void kernel_launch(void* const* d_in, const int* in_sizes, int n_in,
                              void* d_out, int out_size, void* d_ws, size_t ws_size,
                              hipStream_t stream) {
    const float* inputs  = (const float*)d_in[0];
    const float* acc_w   = (const float*)d_in[1];
    const float* acc_b   = (const float*)d_in[2];
    const float* gyro_w  = (const float*)d_in[3];
    const float* gyro_b  = (const float*)d_in[4];
    const float* pos_emb = (const float*)d_in[5];
    const float* ln_g    = (const float*)d_in[6];
    const float* ln_b    = (const float*)d_in[7];
    const float* pc1_w   = (const float*)d_in[8];
    const float* pc1_b   = (const float*)d_in[9];
    const float* dw_w    = (const float*)d_in[10];
    const float* dw_b    = (const float*)d_in[11];
    const float* bn_g    = (const float*)d_in[12];
    const float* bn_b    = (const float*)d_in[13];
    const float* bn_mean = (const float*)d_in[14];
    const float* bn_var  = (const float*)d_in[15];
    const float* Ap      = (const float*)d_in[16];
    const float* Bp      = (const float*)d_in[17];
    const float* Cp      = (const float*)d_in[18];
    const float* Dp      = (const float*)d_in[19];
    const float* pc2_w   = (const float*)d_in[20];
    const float* pc2_b   = (const float*)d_in[21];
    const float* fln_g   = (const float*)d_in[22];
    const float* fln_b   = (const float*)d_in[23];
    const float* hw1     = (const float*)d_in[24];
    const float* hb1     = (const float*)d_in[25];
    const float* hw2     = (const float*)d_in[26];
    const float* hb2     = (const float*)d_in[27];

    const size_t nx  = (size_t)BB * SS * DD;   // 8388608
    const size_t nxc = (size_t)BB * SS * EE;   // 16777216

    ushort_t* wsu = (ushort_t*)d_ws;
    ushort_t* xb   = wsu;                       // bf16 x [M,128]
    ushort_t* xc0  = xb + nx;                   // bf16 xcT ping
    ushort_t* xc1  = xc0 + nxc;                 // bf16 xcT pong
    ushort_t* wpk1 = xc1 + nxc;
    ushort_t* wpk2 = wpk1 + 3 * 32768;
    float* sparm   = (float*)(wpk2 + 3 * 32768);  // [3][256][12]
    float* partial = sparm + 3 * 256 * 12;

    __bf16* x    = (__bf16*)xb;
    __bf16* xcT0 = (__bf16*)xc0;
    __bf16* xcT1 = (__bf16*)xc1;

    k_pack<<<99, 256, 0, stream>>>(pc1_w, pc2_w, dw_w, dw_b, bn_g, bn_b,
                                   bn_mean, bn_var, Ap, Bp, Cp, Dp,
                                   wpk1, wpk2, sparm);

    // stem + layer-0 LN/pc1 tail -> xcT0
    k_stem_mfma<<<1024, 256, 0, stream>>>(inputs, acc_w, acc_b, gyro_w, gyro_b,
                                          pos_emb, x,
                                          ln_g, ln_b, wpk1, pc1_b, xcT0);

    // layer 0: reads xcT0, tail writes layer-1 xcT1
    k_scan_pc2<1><<<dim3(8, BB), 512, 0, stream>>>(
        xcT0, wpk2, sparm,
        pc2_b, x,
        ln_g + DD, ln_b + DD, wpk1 + 32768, pc1_b + EE, xcT1);

    // layer 1: reads xcT1, tail writes layer-2 xcT0
    k_scan_pc2<1><<<dim3(8, BB), 512, 0, stream>>>(
        xcT1, wpk2 + 32768, sparm + 256 * 12,
        pc2_b + DD, x,
        ln_g + 2 * DD, ln_b + 2 * DD, wpk1 + 2 * 32768, pc1_b + 2 * EE, xcT0);

    // layer 2: reads xcT0, no tail
    k_scan_pc2<0><<<dim3(8, BB), 512, 0, stream>>>(
        xcT0, wpk2 + 2 * 32768, sparm + 2 * 256 * 12,
        pc2_b + 2 * DD, x,
        nullptr, nullptr, nullptr, nullptr, nullptr);

    k_finln_s1<<<dim3(8, BB), 256, 0, stream>>>(x, partial);
    k_head<<<BB, 256, 0, stream>>>(partial, fln_g, fln_b, hw1, hb1, hw2, hb2,
                                   (float*)d_out);
}